// Round 13
// baseline (323.189 us; speedup 1.0000x reference)
//
#include <hip/hip_runtime.h>
#include <hip/hip_bf16.h>
#include <hip/hip_fp16.h>
#include <math.h>

#define N_NODES 100000
#define N_EDGES 3200000
#define N_GRAPHS 512
#define BN_EPS 1e-5f
#define NBIN ((N_NODES + 511) / 512)            // 196 bins of 512 nodes
#define CHUNK 8192                              // edges per chunk
#define NCHUNK ((N_EDGES + CHUNK - 1) / CHUNK)  // 391
#define STORE_CAP (N_EDGES + 16 * NBIN * NCHUNK)  // padded store capacity
#define NMMB ((N_NODES + 63) / 64)              // 1563 mfma blocks
#define NB2 3125                                // agg2 blocks
#define NB2P 3136                               // padded stride
#define A1CAP 1024                              // LDS idx cap, 16-node span (~528 avg)
#define A2CAP 2048                              // LDS idx cap, 32-node span (~1056 avg)
#define A3CAP 2048                              // LDS idx cap, 32-node span

typedef _Float16 half8_t __attribute__((ext_vector_type(8)));
typedef float float4_t __attribute__((ext_vector_type(4)));

struct alignas(8) h4 { __half2 a, b; };
struct alignas(16) h8s { __half2 h[4]; };

// NOTE (r6/r7 lesson): NO nontemporal hints anywhere — nt stores break L2
// write-combining on scattered writes; nt loads raise latency on dependent chains.
// ys2/u2 are UNIFIED [N][32]-half rows (64B = one cache line): agg3 visits each
// edge ONCE, full line utilization (r12 2-plane scheme visited twice at 50% util).

// ---------------- CSR build: padded single-scatter radix, 512-node bins ----------------

__global__ void k_hist2(const int* __restrict__ dst, int* __restrict__ hists) {
    __shared__ int h[NBIN];
    for (int i = threadIdx.x; i < NBIN; i += blockDim.x) h[i] = 0;
    __syncthreads();
    int e0 = blockIdx.x * CHUNK;
    int e1 = min(e0 + CHUNK, N_EDGES);
    int e = e0 + threadIdx.x * 8;
    if (e + 8 <= e1) {
        int4 d0 = *(const int4*)(dst + e);
        int4 d1 = *(const int4*)(dst + e + 4);
        atomicAdd(&h[d0.x >> 9], 1); atomicAdd(&h[d0.y >> 9], 1);
        atomicAdd(&h[d0.z >> 9], 1); atomicAdd(&h[d0.w >> 9], 1);
        atomicAdd(&h[d1.x >> 9], 1); atomicAdd(&h[d1.y >> 9], 1);
        atomicAdd(&h[d1.z >> 9], 1); atomicAdd(&h[d1.w >> 9], 1);
    } else {
        for (; e < e1; ++e) atomicAdd(&h[dst[e] >> 9], 1);
    }
    __syncthreads();
    for (int i = threadIdx.x; i < NBIN; i += blockDim.x)
        hists[i * NCHUNK + blockIdx.x] = h[i];
}

__global__ void k_scan2(int* __restrict__ hists, int* __restrict__ ghist) {
    int b = blockIdx.x;
    int lane = threadIdx.x;   // 64 threads
    int carry = 0;
    int base = b * NCHUNK;
    for (int c0 = 0; c0 < NCHUNK; c0 += 64) {
        int c = c0 + lane;
        int v = (c < NCHUNK) ? hists[base + c] : 0;
        int pv = (v + 15) & ~15;
        int inc = pv;
#pragma unroll
        for (int off = 1; off < 64; off <<= 1) {
            int u = __shfl_up(inc, off, 64);
            if (lane >= off) inc += u;
        }
        if (c < NCHUNK) hists[base + c] = inc - pv + carry;
        carry += __shfl(inc, 63, 64);
    }
    if (lane == 0) ghist[b] = carry;   // padded bin total
}

__global__ void k_binscan(const int* __restrict__ ghist, int* __restrict__ bbase) {
    __shared__ int sd[512];
    int t = threadIdx.x;
    int v = (t < NBIN) ? ghist[t] : 0;
    sd[t] = v;
    __syncthreads();
    for (int off = 1; off < 512; off <<= 1) {
        int u = (t >= off) ? sd[t - off] : 0;
        __syncthreads();
        sd[t] += u;
        __syncthreads();
    }
    if (t < NBIN) bbase[t] = sd[t] - v;
    if (t == 511) bbase[NBIN] = sd[511];   // padded grand total
}

__global__ void k_scatter(const int* __restrict__ src, const int* __restrict__ dst,
                          const int* __restrict__ bbase, const int* __restrict__ hists,
                          int* __restrict__ store) {
    __shared__ int cur[NBIN];
    for (int i = threadIdx.x; i < NBIN; i += blockDim.x)
        cur[i] = bbase[i] + hists[i * NCHUNK + blockIdx.x];
    __syncthreads();
    int e0 = blockIdx.x * CHUNK;
    int e1 = min(e0 + CHUNK, N_EDGES);
    int e = e0 + threadIdx.x * 8;
    if (e + 8 <= e1) {
        int4 d0 = *(const int4*)(dst + e), d1 = *(const int4*)(dst + e + 4);
        int4 s0 = *(const int4*)(src + e), s1 = *(const int4*)(src + e + 4);
        int dd[8] = {d0.x, d0.y, d0.z, d0.w, d1.x, d1.y, d1.z, d1.w};
        int sv[8] = {s0.x, s0.y, s0.z, s0.w, s1.x, s1.y, s1.z, s1.w};
#pragma unroll
        for (int j = 0; j < 8; ++j) {
            int d = dd[j];
            int b = d >> 9;
            int pos = atomicAdd(&cur[b], 1);
            store[pos] = (sv[j] << 9) | (d & 511);
        }
    } else {
        for (; e < e1; ++e) {
            int d = dst[e];
            int b = d >> 9;
            int pos = atomicAdd(&cur[b], 1);
            store[pos] = (src[e] << 9) | (d & 511);
        }
    }
    __syncthreads();
    for (int i = threadIdx.x; i < NBIN; i += blockDim.x) {
        int p = cur[i];
        int end = (p + 15) & ~15;
        for (; p < end; ++p) store[p] = -1;
    }
}

__global__ void k_csr_build(const int* __restrict__ bbase, const int* __restrict__ store,
                            const float* __restrict__ x, int* __restrict__ offs,
                            int* __restrict__ ends, float* __restrict__ dis,
                            float* __restrict__ rdis, float4* __restrict__ xd,
                            int* __restrict__ csr) {
    __shared__ int cnt[512], cur[512], wsum[4];
    int b = blockIdx.x;
    int n0 = b << 9;
    int e0 = bbase[b], e1 = bbase[b + 1];
    int t = threadIdx.x;
    int lane = t & 63, wid = t >> 6;
    if (t < 512) cnt[t] = 0;
    __syncthreads();
    for (int e = e0 + t; e < e1; e += 4096) {
        int p[4];
#pragma unroll
        for (int j = 0; j < 4; ++j)
            p[j] = (e + 1024 * j < e1) ? store[e + 1024 * j] : -1;
#pragma unroll
        for (int j = 0; j < 4; ++j)
            if (p[j] >= 0) atomicAdd(&cnt[p[j] & 511], 1);
    }
    __syncthreads();
    int c0 = 0, c1 = 0, pair = 0, inc = 0;
    if (t < 256) {
        c0 = cnt[2 * t];
        c1 = cnt[2 * t + 1];
        pair = c0 + c1;
        inc = pair;
#pragma unroll
        for (int off = 1; off < 64; off <<= 1) {
            int u = __shfl_up(inc, off, 64);
            if (lane >= off) inc += u;
        }
        if (lane == 63) wsum[wid] = inc;
    }
    __syncthreads();
    if (t < 256) {
        int wo = 0;
        for (int w = 0; w < wid; ++w) wo += wsum[w];
        int ex = inc - pair + wo;
        cur[2 * t] = ex;
        cur[2 * t + 1] = ex + c0;
#pragma unroll
        for (int j = 0; j < 2; ++j) {
            int n = n0 + 2 * t + j;
            int cc = j ? c1 : c0;
            int exx = j ? ex + c0 : ex;
            if (n < N_NODES) {
                offs[n] = e0 + exx;
                ends[n] = e0 + exx + cc;
                float dn = rsqrtf(1.0f + (float)cc);
                dis[n] = dn;
                rdis[n] = sqrtf(1.0f + (float)cc);
                float2 xv = *(const float2*)(x + 2 * (size_t)n);
                xd[n] = make_float4(dn * xv.x, dn * xv.y, dn, 0.f);
            } else if (n == N_NODES) {
                xd[N_NODES] = make_float4(0.f, 0.f, 0.f, 0.f);
            }
        }
    }
    __syncthreads();
    for (int e = e0 + t; e < e1; e += 4096) {
        int p[4];
#pragma unroll
        for (int j = 0; j < 4; ++j)
            p[j] = (e + 1024 * j < e1) ? store[e + 1024 * j] : -1;
#pragma unroll
        for (int j = 0; j < 4; ++j)
            if (p[j] >= 0) {
                int pos = e0 + atomicAdd(&cur[p[j] & 511], 1);
                csr[pos] = p[j] >> 9;
            }
    }
}

// ---------------- layer 1: 16 nodes/block, LDS-staged csr indices ----------------

__global__ void k_agg1(const float4* __restrict__ xd, const int* __restrict__ offs,
                       const int* __restrict__ ends, const int* __restrict__ csr,
                       const float* __restrict__ W1, const float* __restrict__ b1,
                       float* __restrict__ svec, __half* __restrict__ ys1) {
    __shared__ float sW[16], sb[8];
    __shared__ int sidx[A1CAP], soff[16], send[16];
    int t = threadIdx.x;
    int n0 = blockIdx.x * 16;
    if (t < 16) { sW[t] = W1[t]; soff[t] = offs[n0 + t]; send[t] = ends[n0 + t]; }
    if (t >= 16 && t < 24) sb[t - 16] = b1[t - 16];
    __syncthreads();
    int base = soff[0];
    int span = send[15] - base;
    int cap = min(span, A1CAP);
    for (int i = t; i < cap; i += 256) sidx[i] = csr[base + i];
    __syncthreads();

    int nl = t >> 4;          // node 0..15
    int lane16 = t & 15;      // 16 edge groups per node
    int node = n0 + nl;
    int rb = soff[nl] - base;
    int re = send[nl] - base;
    float ax = 0.f, ay = 0.f, as = 0.f;
    for (int r = rb + lane16; r < re; r += 64) {
        int s[4];
#pragma unroll
        for (int j = 0; j < 4; ++j) {
            int rr = r + 16 * j;
            s[j] = (rr < re) ? ((rr < A1CAP) ? sidx[rr] : csr[base + rr]) : N_NODES;
        }
        float4 v[4];
#pragma unroll
        for (int j = 0; j < 4; ++j) v[j] = xd[s[j]];
#pragma unroll
        for (int j = 0; j < 4; ++j) {
            ax += v[j].x;
            ay += v[j].y;
            as += v[j].z;
        }
    }
#pragma unroll
    for (int off = 1; off < 16; off <<= 1) {
        ax += __shfl_xor(ax, off, 64);
        ay += __shfl_xor(ay, off, 64);
        as += __shfl_xor(as, off, 64);
    }
    if (lane16 == 0) {
        float4 xn = xd[node];
        float dn = xn.z;
        float u0x = dn * (ax + xn.x);
        float u0y = dn * (ay + xn.y);
        svec[node] = dn * (as + xn.z);
        float y[8];
#pragma unroll
        for (int f = 0; f < 8; ++f)
            y[f] = dn * fmaxf(u0x * sW[f] + u0y * sW[8 + f] + sb[f], 0.f);
        h8s o;
#pragma unroll
        for (int q = 0; q < 4; ++q) o.h[q] = __floats2half2_rn(y[2 * q], y[2 * q + 1]);
        *(h8s*)(ys1 + (size_t)node * 8) = o;
    }
}

// ---------------- BN stats width 8: vectorized h8s reads + shfl reduce ----------------

__global__ void k_stats8v(const __half* __restrict__ ys1, const float* __restrict__ rdis,
                          float* __restrict__ stats) {
    int t = threadIdx.x;   // 256
    float s[8] = {0, 0, 0, 0, 0, 0, 0, 0};
    float s2[8] = {0, 0, 0, 0, 0, 0, 0, 0};
    for (int n = blockIdx.x * 256 + t; n < N_NODES; n += gridDim.x * 256) {
        float r = rdis[n];
        h8s v = *(const h8s*)(ys1 + (size_t)n * 8);
#pragma unroll
        for (int q = 0; q < 4; ++q) {
            float v0 = __low2float(v.h[q]) * r;
            float v1 = __high2float(v.h[q]) * r;
            s[2 * q] += v0;      s2[2 * q] += v0 * v0;
            s[2 * q + 1] += v1;  s2[2 * q + 1] += v1 * v1;
        }
    }
#pragma unroll
    for (int off = 1; off < 64; off <<= 1)
#pragma unroll
        for (int k = 0; k < 8; ++k) {
            s[k] += __shfl_xor(s[k], off, 64);
            s2[k] += __shfl_xor(s2[k], off, 64);
        }
    __shared__ float sm[16];
    if (t < 16) sm[t] = 0.f;
    __syncthreads();
    if ((t & 63) == 0) {
#pragma unroll
        for (int k = 0; k < 8; ++k) {
            atomicAdd(&sm[k], s[k]);
            atomicAdd(&sm[8 + k], s2[k]);
        }
    }
    __syncthreads();
    if (t < 16) atomicAdd(&stats[t], sm[t]);
}

// ---------------- prep2: bn fold into W2; zero row ys1[N] ----------------

__global__ void k_prep2(const float* __restrict__ stats, const float* __restrict__ gamma,
                        const float* __restrict__ beta, const float* __restrict__ W2,
                        float* __restrict__ W2p, float* __restrict__ cw2,
                        __half* __restrict__ ys1) {
    __shared__ float a1[8], c1[8];
    int t = threadIdx.x;   // 256
    if (t < 8) {
        float inv_n = 1.0f / (float)N_NODES;
        float m = stats[t] * inv_n;
        float v = stats[8 + t] * inv_n - m * m;
        float a = gamma[t] * rsqrtf(v + BN_EPS);
        a1[t] = a;
        c1[t] = beta[t] - m * a;
    }
    __syncthreads();
    W2p[t] = a1[t >> 5] * W2[t];    // 8x32 = 256
    if (t < 32) {
        float cb = 0.f;
#pragma unroll
        for (int i = 0; i < 8; ++i) cb += c1[i] * W2[i * 32 + t];
        cw2[t] = cb;
    }
    if (t == 128) *(int4*)(ys1 + (size_t)N_NODES * 8) = make_int4(0, 0, 0, 0);
}

// ---------------- layer 2: 32 nodes/block, LDS-staged csr, fast/tail loop split ----------------
// ys2 written as UNIFIED [N][32]-half rows

__global__ void k_agg2(const __half* __restrict__ ys1, const int* __restrict__ offs,
                       const int* __restrict__ ends, const int* __restrict__ csr,
                       const float* __restrict__ dis, const float* __restrict__ svec,
                       const float* __restrict__ W2p, const float* __restrict__ cw2,
                       const float* __restrict__ b2, __half* __restrict__ ys2,
                       float* __restrict__ part2) {
    __shared__ float sW[256], sC[32], sB[32], sm2[64];
    __shared__ int sidx[A2CAP], soff[32], send[32];
    int t = threadIdx.x;
    int n0 = blockIdx.x * 32;
    sW[t] = W2p[t];
    if (t < 32) {
        sC[t] = cw2[t]; sB[t] = b2[t];
        soff[t] = offs[n0 + t]; send[t] = ends[n0 + t];
    }
    if (t < 64) sm2[t] = 0.f;
    __syncthreads();
    int base = soff[0];
    int span = send[31] - base;
    int cap = min(span, A2CAP);
    for (int i = t; i < cap; i += 256) sidx[i] = csr[base + i];
    __syncthreads();

    int nl = t >> 3;          // node 0..31
    int lane8 = t & 7;        // 8 edge groups
    int node = n0 + nl;
    int rb = soff[nl] - base;
    int re = send[nl] - base;
    float a[8] = {0, 0, 0, 0, 0, 0, 0, 0};
    int r = rb + lane8;
    if (span <= A2CAP) {   // wave-uniform: no cap fallback predicate
        for (; r + 24 < re; r += 32) {   // fast path: all 4 slots valid, no guards
            int s0 = sidx[r], s1 = sidx[r + 8], s2i = sidx[r + 16], s3 = sidx[r + 24];
            h8s v0 = *(const h8s*)(ys1 + (size_t)s0 * 8);
            h8s v1 = *(const h8s*)(ys1 + (size_t)s1 * 8);
            h8s v2 = *(const h8s*)(ys1 + (size_t)s2i * 8);
            h8s v3 = *(const h8s*)(ys1 + (size_t)s3 * 8);
#pragma unroll
            for (int q = 0; q < 4; ++q) {
                a[2 * q] += __low2float(v0.h[q]) + __low2float(v1.h[q]) +
                            __low2float(v2.h[q]) + __low2float(v3.h[q]);
                a[2 * q + 1] += __high2float(v0.h[q]) + __high2float(v1.h[q]) +
                                __high2float(v2.h[q]) + __high2float(v3.h[q]);
            }
        }
        if (r < re) {   // single guarded tail
            int s[4];
#pragma unroll
            for (int j = 0; j < 4; ++j) {
                int rr = r + 8 * j;
                s[j] = (rr < re) ? sidx[rr] : N_NODES;
            }
            h8s v[4];
#pragma unroll
            for (int j = 0; j < 4; ++j) v[j] = *(const h8s*)(ys1 + (size_t)s[j] * 8);
#pragma unroll
            for (int j = 0; j < 4; ++j)
#pragma unroll
                for (int q = 0; q < 4; ++q) {
                    a[2 * q] += __low2float(v[j].h[q]);
                    a[2 * q + 1] += __high2float(v[j].h[q]);
                }
        }
    } else {   // generic path (practically never taken)
        for (; r < re; r += 32) {
            int s[4];
#pragma unroll
            for (int j = 0; j < 4; ++j) {
                int rr = r + 8 * j;
                s[j] = (rr < re) ? ((rr < A2CAP) ? sidx[rr] : csr[base + rr]) : N_NODES;
            }
            h8s v[4];
#pragma unroll
            for (int j = 0; j < 4; ++j) v[j] = *(const h8s*)(ys1 + (size_t)s[j] * 8);
#pragma unroll
            for (int j = 0; j < 4; ++j)
#pragma unroll
                for (int q = 0; q < 4; ++q) {
                    a[2 * q] += __low2float(v[j].h[q]);
                    a[2 * q + 1] += __high2float(v[j].h[q]);
                }
        }
    }
    if (lane8 == 0) {   // self-loop
        h8s v = *(const h8s*)(ys1 + (size_t)node * 8);
#pragma unroll
        for (int q = 0; q < 4; ++q) {
            a[2 * q] += __low2float(v.h[q]);
            a[2 * q + 1] += __high2float(v.h[q]);
        }
    }
#pragma unroll
    for (int off = 1; off < 8; off <<= 1)
#pragma unroll
        for (int k = 0; k < 8; ++k) a[k] += __shfl_xor(a[k], off, 64);
    int lane = t & 63;
    int nsub = lane >> 3;
    int lb = nsub << 3;
    float u[8];
#pragma unroll
    for (int i = 0; i < 8; ++i) u[i] = __shfl(a[i], lb, 64);
    float dn = dis[node];
    float sv = svec[node];
#pragma unroll
    for (int i = 0; i < 8; ++i) u[i] *= dn;
    int c0 = (lane & 7) * 4;
    float hh[4], hs2[4];
#pragma unroll
    for (int k = 0; k < 4; ++k) {
        int col = c0 + k;
        float conv = sB[col] + sv * sC[col];
#pragma unroll
        for (int i = 0; i < 8; ++i) conv += u[i] * sW[i * 32 + col];
        hh[k] = fmaxf(conv, 0.f);
        hs2[k] = hh[k] * hh[k];
    }
    h4 o;
    o.a = __floats2half2_rn(dn * hh[0], dn * hh[1]);
    o.b = __floats2half2_rn(dn * hh[2], dn * hh[3]);
    *(h4*)(ys2 + (size_t)node * 32 + c0) = o;   // unified row store

    // fused BN stats (over pre-dn relu output): reduce across the 8 nodes of the wave
    float hs[4];
#pragma unroll
    for (int k = 0; k < 4; ++k) hs[k] = hh[k];
#pragma unroll
    for (int off = 8; off < 64; off <<= 1)
#pragma unroll
        for (int k = 0; k < 4; ++k) {
            hs[k] += __shfl_xor(hs[k], off, 64);
            hs2[k] += __shfl_xor(hs2[k], off, 64);
        }
    if (nsub == 0) {
#pragma unroll
        for (int k = 0; k < 4; ++k) {
            atomicAdd(&sm2[c0 + k], hs[k]);
            atomicAdd(&sm2[32 + c0 + k], hs2[k]);
        }
    }
    __syncthreads();
    if (t < 64) part2[(size_t)t * NB2P + blockIdx.x] = sm2[t];
}

__global__ void k_red32(const float* __restrict__ part2, float* __restrict__ stats2) {
    int i = blockIdx.x;   // 0..63
    int t = threadIdx.x;  // 256
    float s = 0.f;
    for (int b = t; b < NB2; b += 256) s += part2[(size_t)i * NB2P + b];
    __shared__ float sm[256];
    sm[t] = s;
    __syncthreads();
    for (int st = 128; st > 0; st >>= 1) {
        if (t < st) sm[t] += sm[t + st];
        __syncthreads();
    }
    if (t == 0) stats2[i] = sm[0];
}

// ---------------- prep3 ----------------

__global__ void k_prep3(const float* __restrict__ stats, const float* __restrict__ gamma,
                        const float* __restrict__ beta, const float* __restrict__ W3,
                        __half* __restrict__ wfrag, float* __restrict__ cw3,
                        __half* __restrict__ ys2) {
    __shared__ float a2[32], c2[32];
    int t = threadIdx.x;   // 512
    if (t < 32) {
        float inv_n = 1.0f / (float)N_NODES;
        float m = stats[t] * inv_n;
        float v = stats[32 + t] * inv_n - m * m;
        float a = gamma[t] * rsqrtf(v + BN_EPS);
        a2[t] = a;
        c2[t] = beta[t] - m * a;
    }
    __syncthreads();
    {
        int g = t >> 6, kq = (t >> 4) & 3, c = t & 15;
#pragma unroll
        for (int j = 0; j < 8; ++j) {
            int k = kq * 8 + j;
            wfrag[(size_t)t * 8 + j] = __float2half(a2[k] * W3[k * 128 + g * 16 + c]);
        }
    }
    if (t < 128) {
        float cb = 0.f;
#pragma unroll
        for (int k = 0; k < 32; ++k) cb += c2[k] * W3[k * 128 + t];
        cw3[t] = cb;
    }
    // zero sentinel row N (32 halves)
    if (t >= 480 && t < 496) {
        int idx = t - 480;   // 0..15 half2 slots
        ((__half2*)(ys2 + (size_t)N_NODES * 32))[idx] =
            __half2{__float2half(0.f), __float2half(0.f)};
    }
}

// ---------------- layer 3 aggregation: SINGLE PASS over unified 64B rows ----------------
// 32 nodes / 512-thread block; 16 lanes/node = 8 eg x 2 chunk; chunk-pair lanes read
// the two 32B halves of the SAME 64B row (one line touch per edge). LDS-staged csr.

__global__ void k_agg3(const __half* __restrict__ ys2, const int* __restrict__ offs,
                       const int* __restrict__ ends, const int* __restrict__ csr,
                       const float* __restrict__ dis, __half* __restrict__ u2) {
    __shared__ int sidx[A3CAP], soff[32], send[32];
    int t = threadIdx.x;   // 512
    int n0 = blockIdx.x * 32;
    if (t < 32) { soff[t] = offs[n0 + t]; send[t] = ends[n0 + t]; }
    __syncthreads();
    int base = soff[0];
    int span = send[31] - base;
    int cap = min(span, A3CAP);
    for (int i = t; i < cap; i += 512) sidx[i] = csr[base + i];
    __syncthreads();

    int nl = t >> 4;          // node 0..31
    int lane16 = t & 15;
    int eg = lane16 >> 1;     // 8 edge groups
    int chunk = lane16 & 1;   // 2 x 32B per 64B row
    int node = n0 + nl;
    int rb = soff[nl] - base;
    int re = send[nl] - base;
    float a[16];
#pragma unroll
    for (int k = 0; k < 16; ++k) a[k] = 0.f;
    const __half* hp = ys2 + chunk * 16;   // this lane's 16-feature half
    int r = rb + eg;
    if (span <= A3CAP) {   // wave-uniform specialization: no cap fallback
        for (; r + 24 < re; r += 32) {   // fast path: no guards
            int s0 = sidx[r], s1 = sidx[r + 8], s2i = sidx[r + 16], s3 = sidx[r + 24];
            h8s v0a = *(const h8s*)(hp + (size_t)s0 * 32);
            h8s v0b = *(const h8s*)(hp + (size_t)s0 * 32 + 8);
            h8s v1a = *(const h8s*)(hp + (size_t)s1 * 32);
            h8s v1b = *(const h8s*)(hp + (size_t)s1 * 32 + 8);
            h8s v2a = *(const h8s*)(hp + (size_t)s2i * 32);
            h8s v2b = *(const h8s*)(hp + (size_t)s2i * 32 + 8);
            h8s v3a = *(const h8s*)(hp + (size_t)s3 * 32);
            h8s v3b = *(const h8s*)(hp + (size_t)s3 * 32 + 8);
#pragma unroll
            for (int q = 0; q < 4; ++q) {
                a[2 * q] += __low2float(v0a.h[q]) + __low2float(v1a.h[q]) +
                            __low2float(v2a.h[q]) + __low2float(v3a.h[q]);
                a[2 * q + 1] += __high2float(v0a.h[q]) + __high2float(v1a.h[q]) +
                                __high2float(v2a.h[q]) + __high2float(v3a.h[q]);
                a[8 + 2 * q] += __low2float(v0b.h[q]) + __low2float(v1b.h[q]) +
                                __low2float(v2b.h[q]) + __low2float(v3b.h[q]);
                a[8 + 2 * q + 1] += __high2float(v0b.h[q]) + __high2float(v1b.h[q]) +
                                    __high2float(v2b.h[q]) + __high2float(v3b.h[q]);
            }
        }
        if (r < re) {   // single guarded tail
            int s[4];
#pragma unroll
            for (int j = 0; j < 4; ++j) {
                int rr = r + 8 * j;
                s[j] = (rr < re) ? sidx[rr] : N_NODES;
            }
#pragma unroll
            for (int j = 0; j < 4; ++j) {
                h8s va = *(const h8s*)(hp + (size_t)s[j] * 32);
                h8s vb = *(const h8s*)(hp + (size_t)s[j] * 32 + 8);
#pragma unroll
                for (int q = 0; q < 4; ++q) {
                    a[2 * q] += __low2float(va.h[q]);
                    a[2 * q + 1] += __high2float(va.h[q]);
                    a[8 + 2 * q] += __low2float(vb.h[q]);
                    a[8 + 2 * q + 1] += __high2float(vb.h[q]);
                }
            }
        }
    } else {   // generic path (practically never taken)
        for (; r < re; r += 32) {
            int s[4];
#pragma unroll
            for (int j = 0; j < 4; ++j) {
                int rr = r + 8 * j;
                s[j] = (rr < re) ? ((rr < A3CAP) ? sidx[rr] : csr[base + rr]) : N_NODES;
            }
#pragma unroll
            for (int j = 0; j < 4; ++j) {
                h8s va = *(const h8s*)(hp + (size_t)s[j] * 32);
                h8s vb = *(const h8s*)(hp + (size_t)s[j] * 32 + 8);
#pragma unroll
                for (int q = 0; q < 4; ++q) {
                    a[2 * q] += __low2float(va.h[q]);
                    a[2 * q + 1] += __high2float(va.h[q]);
                    a[8 + 2 * q] += __low2float(vb.h[q]);
                    a[8 + 2 * q + 1] += __high2float(vb.h[q]);
                }
            }
        }
    }
    if (eg == 0) {   // self-loop: each chunk lane adds its 32B half
        h8s va = *(const h8s*)(hp + (size_t)node * 32);
        h8s vb = *(const h8s*)(hp + (size_t)node * 32 + 8);
#pragma unroll
        for (int q = 0; q < 4; ++q) {
            a[2 * q] += __low2float(va.h[q]);
            a[2 * q + 1] += __high2float(va.h[q]);
            a[8 + 2 * q] += __low2float(vb.h[q]);
            a[8 + 2 * q + 1] += __high2float(vb.h[q]);
        }
    }
    // reduce over eg (tid bits 1-3); chunk bit preserved
#pragma unroll
    for (int off = 2; off < 16; off <<= 1)
#pragma unroll
        for (int k = 0; k < 16; ++k) a[k] += __shfl_xor(a[k], off, 64);
    if (eg == 0) {
        float dn = dis[node];
        h8s oa, ob;
#pragma unroll
        for (int q = 0; q < 4; ++q) {
            oa.h[q] = __floats2half2_rn(dn * a[2 * q], dn * a[2 * q + 1]);
            ob.h[q] = __floats2half2_rn(dn * a[8 + 2 * q], dn * a[8 + 2 * q + 1]);
        }
        *(h8s*)(u2 + (size_t)node * 32 + chunk * 16) = oa;
        *(h8s*)(u2 + (size_t)node * 32 + chunk * 16 + 8) = ob;
    }
}

// ---------------- layer 3 transform via MFMA + fused BN-stats + fused POOLING ----------------

__global__ void k_mm_mfma(const __half* __restrict__ u2, const __half* __restrict__ wfrag,
                          const float* __restrict__ cw3, const float* __restrict__ b3,
                          const float* __restrict__ svec, const int* __restrict__ batch,
                          float* __restrict__ spart, int* __restrict__ gmax,
                          int* __restrict__ gmin) {
    __shared__ float sm[256];
    int t = threadIdx.x;
    int wave = t >> 6;
    int lane = t & 63;
    int n0 = (blockIdx.x * 4 + wave) * 16;
    bool active = n0 < N_NODES;
    int m = lane & 15;
    int kq = lane >> 4;
    float ss[8] = {0, 0, 0, 0, 0, 0, 0, 0};
    float ss2[8] = {0, 0, 0, 0, 0, 0, 0, 0};

    if (active) {
        // unified u2 rows: features kq*8 .. kq*8+7
        half8_t af = *(const half8_t*)(u2 + (size_t)(n0 + m) * 32 + kq * 8);
        float4_t accs[8];
#pragma unroll
        for (int g = 0; g < 8; ++g) {
            float4_t acc = {0.f, 0.f, 0.f, 0.f};
            half8_t bf = *(const half8_t*)(wfrag + (size_t)((g * 4 + kq) * 16 + m) * 8);
            accs[g] = __builtin_amdgcn_mfma_f32_16x16x32_f16(af, bf, acc, 0, 0, 0);
        }
        float sv[4];
#pragma unroll
        for (int r = 0; r < 4; ++r) sv[r] = svec[n0 + kq * 4 + r];

        int b_first = batch[n0];
        int b_last = batch[n0 + 15];
        bool uni = (b_first == b_last);
        int bnr[4];
        if (!uni) {
#pragma unroll
            for (int r = 0; r < 4; ++r) bnr[r] = batch[n0 + kq * 4 + r];
        }
        float ymx[8], ymn[8];
#pragma unroll
        for (int g = 0; g < 8; ++g) {
            float cwf = cw3[g * 16 + m];
            float bf3 = b3[g * 16 + m];
            float mx = 0.f, mn = INFINITY;
#pragma unroll
            for (int r = 0; r < 4; ++r) {
                float y = fmaxf(accs[g][r] + sv[r] * cwf + bf3, 0.f);
                ss[g] += y;
                ss2[g] += y * y;
                mx = fmaxf(mx, y);
                mn = fminf(mn, y);
                if (!uni) {
                    int yb = __float_as_int(y);
                    atomicMax(&gmax[bnr[r] * 128 + g * 16 + m], yb);
                    atomicMin(&gmin[bnr[r] * 128 + g * 16 + m], yb);
                }
            }
            ymx[g] = mx;
            ymn[g] = mn;
        }
        if (uni) {
#pragma unroll
            for (int off = 16; off < 64; off <<= 1)
#pragma unroll
                for (int g = 0; g < 8; ++g) {
                    ymx[g] = fmaxf(ymx[g], __shfl_xor(ymx[g], off, 64));
                    ymn[g] = fminf(ymn[g], __shfl_xor(ymn[g], off, 64));
                }
            if (kq == 0) {
#pragma unroll
                for (int g = 0; g < 8; ++g) {
                    atomicMax(&gmax[b_first * 128 + g * 16 + m], __float_as_int(ymx[g]));
                    atomicMin(&gmin[b_first * 128 + g * 16 + m], __float_as_int(ymn[g]));
                }
            }
        }
    }
#pragma unroll
    for (int off = 16; off < 64; off <<= 1)
#pragma unroll
        for (int g = 0; g < 8; ++g) {
            ss[g] += __shfl_xor(ss[g], off, 64);
            ss2[g] += __shfl_xor(ss2[g], off, 64);
        }
    sm[t] = 0.f;
    __syncthreads();
    if (active && kq == 0) {
#pragma unroll
        for (int g = 0; g < 8; ++g) {
            atomicAdd(&sm[g * 16 + m], ss[g]);
            atomicAdd(&sm[128 + g * 16 + m], ss2[g]);
        }
    }
    __syncthreads();
    spart[(size_t)blockIdx.x * 256 + t] = sm[t];
}

__global__ void k_stats_red(const float* __restrict__ part, float* __restrict__ stats) {
    int i = blockIdx.x;   // 0..255
    int t = threadIdx.x;  // 256
    float s = 0.f;
    for (int b = t; b < NMMB; b += 256) s += part[(size_t)b * 256 + i];
    __shared__ float sm[256];
    sm[t] = s;
    __syncthreads();
    for (int st = 128; st > 0; st >>= 1) {
        if (t < st) sm[t] += sm[t + st];
        __syncthreads();
    }
    if (t == 0) stats[i] = sm[0];
}

// ---------------- fused bn-affine + head + log_softmax ----------------

__device__ __forceinline__ int lower_bound_dev(const int* __restrict__ a, int val) {
    int lo = 0, hi = N_NODES;
    while (lo < hi) {
        int mid = (lo + hi) >> 1;
        if (a[mid] < val) lo = mid + 1; else hi = mid;
    }
    return lo;
}

__global__ void k_poolhead(const int* __restrict__ gmax, const int* __restrict__ gmin,
                           const int* __restrict__ batch, const float* __restrict__ stats,
                           const float* __restrict__ gamma, const float* __restrict__ beta,
                           const float* __restrict__ Wl, const float* __restrict__ bl,
                           float* __restrict__ out) {
    int g = blockIdx.x;
    int f = threadIdx.x;    // 128
    float inv_n = 1.0f / (float)N_NODES;
    float m = stats[f] * inv_n;
    float var = stats[128 + f] * inv_n - m * m;
    float a = gamma[f] * rsqrtf(var + BN_EPS);
    float c = beta[f] - m * a;
    int s = lower_bound_dev(batch, g);
    int e = lower_bound_dev(batch, g + 1);
    float mx = __int_as_float(gmax[g * 128 + f]);
    float mn = __int_as_float(gmin[g * 128 + f]);
    float r;
    if (e > s) r = (a >= 0.f) ? (a * mx + c) : (a * mn + c);
    else r = -INFINITY;
    __shared__ float l[3][128];
    l[0][f] = r * Wl[f * 3 + 0];
    l[1][f] = r * Wl[f * 3 + 1];
    l[2][f] = r * Wl[f * 3 + 2];
    __syncthreads();
    for (int st = 64; st > 0; st >>= 1) {
        if (f < st) {
            l[0][f] += l[0][f + st];
            l[1][f] += l[1][f + st];
            l[2][f] += l[2][f + st];
        }
        __syncthreads();
    }
    if (f == 0) {
        float l0 = l[0][0] + bl[0], l1 = l[1][0] + bl[1], l2 = l[2][0] + bl[2];
        float mxl = fmaxf(l0, fmaxf(l1, l2));
        float lse = mxl + logf(expf(l0 - mxl) + expf(l1 - mxl) + expf(l2 - mxl));
        out[g * 3 + 0] = l0 - lse;
        out[g * 3 + 1] = l1 - lse;
        out[g * 3 + 2] = l2 - lse;
    }
}

// ---------------- launch ----------------

extern "C" void kernel_launch(void* const* d_in, const int* in_sizes, int n_in,
                              void* d_out, int out_size, void* d_ws, size_t ws_size,
                              hipStream_t stream) {
    const float* x   = (const float*)d_in[0];
    const int* ei    = (const int*)d_in[1];
    const int* src   = ei;
    const int* dst   = ei + N_EDGES;
    const int* batch = (const int*)d_in[2];
    const float *W1 = (const float*)d_in[3],  *b1 = (const float*)d_in[4];
    const float *g1 = (const float*)d_in[5],  *be1 = (const float*)d_in[6];
    const float *W2 = (const float*)d_in[7],  *b2 = (const float*)d_in[8];
    const float *g2 = (const float*)d_in[9],  *be2 = (const float*)d_in[10];
    const float *W3 = (const float*)d_in[11], *b3 = (const float*)d_in[12];
    const float *g3 = (const float*)d_in[13], *be3 = (const float*)d_in[14];
    const float *Wl = (const float*)d_in[15], *bl = (const float*)d_in[16];
    float* out = (float*)d_out;

    // workspace carve (4-byte words)
    int* base = (int*)d_ws;
    size_t o = 0;
    float* stats1 = (float*)(base + o); o += 256;
    float* stats2 = (float*)(base + o); o += 256;
    float* stats3 = (float*)(base + o); o += 256;
    int* gmax     = base + o; o += (size_t)N_GRAPHS * 128;
    size_t zero_words = o;                         // zeroed region
    int* gmin     = base + o; o += (size_t)N_GRAPHS * 128;   // memset 0x7F
    int* bbase    = base + o; o += NBIN + 4;
    int* ghist    = base + o; o += NBIN + 4;
    int* hists    = base + o; o += ((size_t)NBIN * NCHUNK + 3) & ~3ULL;
    float* W2p    = (float*)(base + o); o += 256;
    float* cw2    = (float*)(base + o); o += 32;
    __half* wfrag = (__half*)(base + o); o += 2048;
    float* cw3    = (float*)(base + o); o += 128;
    int* offs     = base + o; o += 100000;
    int* ends     = base + o; o += 100000;
    int* store    = base + o; o += STORE_CAP;
    int* csr      = base + o; o += STORE_CAP;
    float* dis    = (float*)(base + o); o += N_NODES;
    float* rdis   = (float*)(base + o); o += N_NODES;
    float* svec   = (float*)(base + o); o += N_NODES;
    float* spart  = (float*)(base + o); o += (size_t)NMMB * 256;
    float* part2  = (float*)(base + o); o += (size_t)64 * NB2P;
    float4* xd    = (float4*)(base + o); o += (size_t)(N_NODES + 1) * 4;
    __half* ys1   = (__half*)(base + o); o += (size_t)(N_NODES + 1) * 4;
    __half* ys2   = (__half*)(base + o); o += (size_t)(N_NODES + 1) * 16;  // [N+1][32] halves
    __half* u2    = (__half*)(base + o); o += (size_t)N_NODES * 16;        // [N][32] halves
    if (ws_size < o * 4) return;

    const int TB = 256;

    hipMemsetAsync(base, 0, zero_words * 4, stream);
    hipMemsetAsync(gmin, 0x7F, (size_t)N_GRAPHS * 128 * 4, stream);

    // CSR build (padded radix, 512-node bins, direct scatter)
    k_hist2<<<NCHUNK, 1024, 0, stream>>>(dst, hists);
    k_scan2<<<NBIN, 64, 0, stream>>>(hists, ghist);
    k_binscan<<<1, 512, 0, stream>>>(ghist, bbase);
    k_scatter<<<NCHUNK, 1024, 0, stream>>>(src, dst, bbase, hists, store);
    k_csr_build<<<NBIN, 1024, 0, stream>>>(bbase, store, x, offs, ends, dis, rdis, xd, csr);

    // layer 1 (16 nodes/block, LDS-staged csr)
    k_agg1<<<N_NODES / 16, TB, 0, stream>>>(xd, offs, ends, csr, W1, b1, svec, ys1);
    k_stats8v<<<64, 256, 0, stream>>>(ys1, rdis, stats1);
    k_prep2<<<1, 256, 0, stream>>>(stats1, g1, be1, W2, W2p, cw2, ys1);

    // layer 2 (32 nodes/block, LDS-staged csr, fast/tail split) with fused BN-stats
    k_agg2<<<NB2, TB, 0, stream>>>(ys1, offs, ends, csr, dis, svec, W2p, cw2, b2, ys2, part2);
    k_red32<<<64, 256, 0, stream>>>(part2, stats2);
    k_prep3<<<1, 512, 0, stream>>>(stats2, g2, be2, W3, wfrag, cw3, ys2);

    // layer 3: single pass over unified 64B rows, 32 nodes / 512-thread block
    k_agg3<<<N_NODES / 32, 512, 0, stream>>>(ys2, offs, ends, csr, dis, u2);
    k_mm_mfma<<<NMMB, 256, 0, stream>>>(u2, wfrag, cw3, b3, svec, batch, spart, gmax, gmin);
    k_stats_red<<<256, 256, 0, stream>>>(spart, stats3);

    // head
    k_poolhead<<<N_GRAPHS, 128, 0, stream>>>(gmax, gmin, batch, stats3, g3, be3, Wl, bl, out);
}

// Round 14
// 308.411 us; speedup vs baseline: 1.0479x; 1.0479x over previous
//
#include <hip/hip_runtime.h>
#include <hip/hip_bf16.h>
#include <hip/hip_fp16.h>
#include <math.h>

#define N_NODES 100000
#define N_EDGES 3200000
#define N_GRAPHS 512
#define BN_EPS 1e-5f
#define NBIN ((N_NODES + 511) / 512)            // 196 bins of 512 nodes
#define CHUNK 8192                              // edges per chunk
#define NCHUNK ((N_EDGES + CHUNK - 1) / CHUNK)  // 391
#define STORE_CAP (N_EDGES + 16 * NBIN * NCHUNK)  // padded store capacity
#define NMMB ((N_NODES + 63) / 64)              // 1563 mfma blocks
#define NB2 3125                                // agg2 blocks
#define NB2P 3136                               // padded stride
#define PLANE2 ((size_t)(N_NODES + 1) * 16)     // ys2 plane stride (halves)
#define PLANEU ((size_t)N_NODES * 16)           // u2 plane stride (halves)
#define A2CAP 2048                              // LDS idx cap, 32-node span (~1056 avg)
#define A3CAP 2048                              // LDS idx cap, 32-node span

typedef _Float16 half8_t __attribute__((ext_vector_type(8)));
typedef float float4_t __attribute__((ext_vector_type(4)));

struct alignas(8) h4 { __half2 a, b; };
struct alignas(16) h8s { __half2 h[4]; };

// NOTE (r6/r7): NO nontemporal hints — nt stores break L2 write-combining on
// scattered writes; nt loads raise latency on dependent chains.
// NOTE (r13): single-pass unified 64B rows REGRESSED (FETCH 29->129MB, occupancy
// 68->32%); the 2-plane L2-resident scheme below is the confirmed structure.

// ---------------- CSR build: padded single-scatter radix, 512-node bins ----------------

__global__ void k_hist2(const int* __restrict__ dst, int* __restrict__ hists) {
    __shared__ int h[NBIN];
    for (int i = threadIdx.x; i < NBIN; i += blockDim.x) h[i] = 0;
    __syncthreads();
    int e0 = blockIdx.x * CHUNK;
    int e1 = min(e0 + CHUNK, N_EDGES);
    int e = e0 + threadIdx.x * 8;
    if (e + 8 <= e1) {
        int4 d0 = *(const int4*)(dst + e);
        int4 d1 = *(const int4*)(dst + e + 4);
        atomicAdd(&h[d0.x >> 9], 1); atomicAdd(&h[d0.y >> 9], 1);
        atomicAdd(&h[d0.z >> 9], 1); atomicAdd(&h[d0.w >> 9], 1);
        atomicAdd(&h[d1.x >> 9], 1); atomicAdd(&h[d1.y >> 9], 1);
        atomicAdd(&h[d1.z >> 9], 1); atomicAdd(&h[d1.w >> 9], 1);
    } else {
        for (; e < e1; ++e) atomicAdd(&h[dst[e] >> 9], 1);
    }
    __syncthreads();
    for (int i = threadIdx.x; i < NBIN; i += blockDim.x)
        hists[i * NCHUNK + blockIdx.x] = h[i];
}

__global__ void k_scan2(int* __restrict__ hists, int* __restrict__ ghist) {
    int b = blockIdx.x;
    int lane = threadIdx.x;   // 64 threads
    int carry = 0;
    int base = b * NCHUNK;
    for (int c0 = 0; c0 < NCHUNK; c0 += 64) {
        int c = c0 + lane;
        int v = (c < NCHUNK) ? hists[base + c] : 0;
        int pv = (v + 15) & ~15;
        int inc = pv;
#pragma unroll
        for (int off = 1; off < 64; off <<= 1) {
            int u = __shfl_up(inc, off, 64);
            if (lane >= off) inc += u;
        }
        if (c < NCHUNK) hists[base + c] = inc - pv + carry;
        carry += __shfl(inc, 63, 64);
    }
    if (lane == 0) ghist[b] = carry;   // padded bin total
}

__global__ void k_binscan(const int* __restrict__ ghist, int* __restrict__ bbase) {
    __shared__ int sd[512];
    int t = threadIdx.x;
    int v = (t < NBIN) ? ghist[t] : 0;
    sd[t] = v;
    __syncthreads();
    for (int off = 1; off < 512; off <<= 1) {
        int u = (t >= off) ? sd[t - off] : 0;
        __syncthreads();
        sd[t] += u;
        __syncthreads();
    }
    if (t < NBIN) bbase[t] = sd[t] - v;
    if (t == 511) bbase[NBIN] = sd[511];   // padded grand total
}

__global__ void k_scatter(const int* __restrict__ src, const int* __restrict__ dst,
                          const int* __restrict__ bbase, const int* __restrict__ hists,
                          int* __restrict__ store) {
    __shared__ int cur[NBIN];
    for (int i = threadIdx.x; i < NBIN; i += blockDim.x)
        cur[i] = bbase[i] + hists[i * NCHUNK + blockIdx.x];
    __syncthreads();
    int e0 = blockIdx.x * CHUNK;
    int e1 = min(e0 + CHUNK, N_EDGES);
    int e = e0 + threadIdx.x * 8;
    if (e + 8 <= e1) {
        int4 d0 = *(const int4*)(dst + e), d1 = *(const int4*)(dst + e + 4);
        int4 s0 = *(const int4*)(src + e), s1 = *(const int4*)(src + e + 4);
        int dd[8] = {d0.x, d0.y, d0.z, d0.w, d1.x, d1.y, d1.z, d1.w};
        int sv[8] = {s0.x, s0.y, s0.z, s0.w, s1.x, s1.y, s1.z, s1.w};
#pragma unroll
        for (int j = 0; j < 8; ++j) {
            int d = dd[j];
            int b = d >> 9;
            int pos = atomicAdd(&cur[b], 1);
            store[pos] = (sv[j] << 9) | (d & 511);
        }
    } else {
        for (; e < e1; ++e) {
            int d = dst[e];
            int b = d >> 9;
            int pos = atomicAdd(&cur[b], 1);
            store[pos] = (src[e] << 9) | (d & 511);
        }
    }
    __syncthreads();
    for (int i = threadIdx.x; i < NBIN; i += blockDim.x) {
        int p = cur[i];
        int end = (p + 15) & ~15;
        for (; p < end; ++p) store[p] = -1;
    }
}

__global__ void k_csr_build(const int* __restrict__ bbase, const int* __restrict__ store,
                            const float* __restrict__ x, int* __restrict__ offs,
                            int* __restrict__ ends, float* __restrict__ dis,
                            float* __restrict__ rdis, float4* __restrict__ xd,
                            int* __restrict__ csr) {
    __shared__ int cnt[512], cur[512], wsum[4];
    int b = blockIdx.x;
    int n0 = b << 9;
    int e0 = bbase[b], e1 = bbase[b + 1];
    int t = threadIdx.x;
    int lane = t & 63, wid = t >> 6;
    if (t < 512) cnt[t] = 0;
    __syncthreads();
    for (int e = e0 + t; e < e1; e += 4096) {
        int p[4];
#pragma unroll
        for (int j = 0; j < 4; ++j)
            p[j] = (e + 1024 * j < e1) ? store[e + 1024 * j] : -1;
#pragma unroll
        for (int j = 0; j < 4; ++j)
            if (p[j] >= 0) atomicAdd(&cnt[p[j] & 511], 1);
    }
    __syncthreads();
    int c0 = 0, c1 = 0, pair = 0, inc = 0;
    if (t < 256) {
        c0 = cnt[2 * t];
        c1 = cnt[2 * t + 1];
        pair = c0 + c1;
        inc = pair;
#pragma unroll
        for (int off = 1; off < 64; off <<= 1) {
            int u = __shfl_up(inc, off, 64);
            if (lane >= off) inc += u;
        }
        if (lane == 63) wsum[wid] = inc;
    }
    __syncthreads();
    if (t < 256) {
        int wo = 0;
        for (int w = 0; w < wid; ++w) wo += wsum[w];
        int ex = inc - pair + wo;
        cur[2 * t] = ex;
        cur[2 * t + 1] = ex + c0;
#pragma unroll
        for (int j = 0; j < 2; ++j) {
            int n = n0 + 2 * t + j;
            int cc = j ? c1 : c0;
            int exx = j ? ex + c0 : ex;
            if (n < N_NODES) {
                offs[n] = e0 + exx;
                ends[n] = e0 + exx + cc;
                float dn = rsqrtf(1.0f + (float)cc);
                dis[n] = dn;
                rdis[n] = sqrtf(1.0f + (float)cc);
                float2 xv = *(const float2*)(x + 2 * (size_t)n);
                xd[n] = make_float4(dn * xv.x, dn * xv.y, dn, 0.f);
            } else if (n == N_NODES) {
                xd[N_NODES] = make_float4(0.f, 0.f, 0.f, 0.f);
            }
        }
    }
    __syncthreads();
    for (int e = e0 + t; e < e1; e += 4096) {
        int p[4];
#pragma unroll
        for (int j = 0; j < 4; ++j)
            p[j] = (e + 1024 * j < e1) ? store[e + 1024 * j] : -1;
#pragma unroll
        for (int j = 0; j < 4; ++j)
            if (p[j] >= 0) {
                int pos = e0 + atomicAdd(&cur[p[j] & 511], 1);
                csr[pos] = p[j] >> 9;
            }
    }
}

// ---------------- layer 1: 32 nodes/block, LDS-staged csr, fast/tail split ----------------
// (mirrors the proven agg2 structure; xd table is 1.6MB = fully L2-resident)

__global__ void k_agg1(const float4* __restrict__ xd, const int* __restrict__ offs,
                       const int* __restrict__ ends, const int* __restrict__ csr,
                       const float* __restrict__ W1, const float* __restrict__ b1,
                       float* __restrict__ svec, __half* __restrict__ ys1) {
    __shared__ float sW[16], sb[8];
    __shared__ int sidx[A2CAP], soff[32], send[32];
    int t = threadIdx.x;   // 256
    int n0 = blockIdx.x * 32;
    if (t < 16) sW[t] = W1[t];
    if (t >= 16 && t < 24) sb[t - 16] = b1[t - 16];
    if (t < 32) { soff[t] = offs[n0 + t]; send[t] = ends[n0 + t]; }
    __syncthreads();
    int base = soff[0];
    int span = send[31] - base;
    int cap = min(span, A2CAP);
    for (int i = t; i < cap; i += 256) sidx[i] = csr[base + i];
    __syncthreads();

    int nl = t >> 3;          // node 0..31
    int lane8 = t & 7;        // 8 edge groups per node
    int node = n0 + nl;
    int rb = soff[nl] - base;
    int re = send[nl] - base;
    float ax = 0.f, ay = 0.f, as = 0.f;
    int r = rb + lane8;
    if (span <= A2CAP) {   // wave-uniform: no cap fallback predicate
        for (; r + 24 < re; r += 32) {   // fast path: no guards
            int s0 = sidx[r], s1 = sidx[r + 8], s2i = sidx[r + 16], s3 = sidx[r + 24];
            float4 v0 = xd[s0], v1 = xd[s1], v2 = xd[s2i], v3 = xd[s3];
            ax += v0.x + v1.x + v2.x + v3.x;
            ay += v0.y + v1.y + v2.y + v3.y;
            as += v0.z + v1.z + v2.z + v3.z;
        }
        if (r < re) {   // single guarded tail
            int s[4];
#pragma unroll
            for (int j = 0; j < 4; ++j) {
                int rr = r + 8 * j;
                s[j] = (rr < re) ? sidx[rr] : N_NODES;
            }
            float4 v[4];
#pragma unroll
            for (int j = 0; j < 4; ++j) v[j] = xd[s[j]];
#pragma unroll
            for (int j = 0; j < 4; ++j) {
                ax += v[j].x;
                ay += v[j].y;
                as += v[j].z;
            }
        }
    } else {   // generic path (practically never taken)
        for (; r < re; r += 32) {
            int s[4];
#pragma unroll
            for (int j = 0; j < 4; ++j) {
                int rr = r + 8 * j;
                s[j] = (rr < re) ? ((rr < A2CAP) ? sidx[rr] : csr[base + rr]) : N_NODES;
            }
            float4 v[4];
#pragma unroll
            for (int j = 0; j < 4; ++j) v[j] = xd[s[j]];
#pragma unroll
            for (int j = 0; j < 4; ++j) {
                ax += v[j].x;
                ay += v[j].y;
                as += v[j].z;
            }
        }
    }
#pragma unroll
    for (int off = 1; off < 8; off <<= 1) {
        ax += __shfl_xor(ax, off, 64);
        ay += __shfl_xor(ay, off, 64);
        as += __shfl_xor(as, off, 64);
    }
    if (lane8 == 0) {
        float4 xn = xd[node];
        float dn = xn.z;
        float u0x = dn * (ax + xn.x);
        float u0y = dn * (ay + xn.y);
        svec[node] = dn * (as + xn.z);
        float y[8];
#pragma unroll
        for (int f = 0; f < 8; ++f)
            y[f] = dn * fmaxf(u0x * sW[f] + u0y * sW[8 + f] + sb[f], 0.f);
        h8s o;
#pragma unroll
        for (int q = 0; q < 4; ++q) o.h[q] = __floats2half2_rn(y[2 * q], y[2 * q + 1]);
        *(h8s*)(ys1 + (size_t)node * 8) = o;
    }
}

// ---------------- BN stats width 8: vectorized h8s reads + shfl reduce ----------------

__global__ void k_stats8v(const __half* __restrict__ ys1, const float* __restrict__ rdis,
                          float* __restrict__ stats) {
    int t = threadIdx.x;   // 256
    float s[8] = {0, 0, 0, 0, 0, 0, 0, 0};
    float s2[8] = {0, 0, 0, 0, 0, 0, 0, 0};
    for (int n = blockIdx.x * 256 + t; n < N_NODES; n += gridDim.x * 256) {
        float r = rdis[n];
        h8s v = *(const h8s*)(ys1 + (size_t)n * 8);
#pragma unroll
        for (int q = 0; q < 4; ++q) {
            float v0 = __low2float(v.h[q]) * r;
            float v1 = __high2float(v.h[q]) * r;
            s[2 * q] += v0;      s2[2 * q] += v0 * v0;
            s[2 * q + 1] += v1;  s2[2 * q + 1] += v1 * v1;
        }
    }
#pragma unroll
    for (int off = 1; off < 64; off <<= 1)
#pragma unroll
        for (int k = 0; k < 8; ++k) {
            s[k] += __shfl_xor(s[k], off, 64);
            s2[k] += __shfl_xor(s2[k], off, 64);
        }
    __shared__ float sm[16];
    if (t < 16) sm[t] = 0.f;
    __syncthreads();
    if ((t & 63) == 0) {
#pragma unroll
        for (int k = 0; k < 8; ++k) {
            atomicAdd(&sm[k], s[k]);
            atomicAdd(&sm[8 + k], s2[k]);
        }
    }
    __syncthreads();
    if (t < 16) atomicAdd(&stats[t], sm[t]);
}

// ---------------- prep2: bn fold into W2; zero row ys1[N] ----------------

__global__ void k_prep2(const float* __restrict__ stats, const float* __restrict__ gamma,
                        const float* __restrict__ beta, const float* __restrict__ W2,
                        float* __restrict__ W2p, float* __restrict__ cw2,
                        __half* __restrict__ ys1) {
    __shared__ float a1[8], c1[8];
    int t = threadIdx.x;   // 256
    if (t < 8) {
        float inv_n = 1.0f / (float)N_NODES;
        float m = stats[t] * inv_n;
        float v = stats[8 + t] * inv_n - m * m;
        float a = gamma[t] * rsqrtf(v + BN_EPS);
        a1[t] = a;
        c1[t] = beta[t] - m * a;
    }
    __syncthreads();
    W2p[t] = a1[t >> 5] * W2[t];    // 8x32 = 256
    if (t < 32) {
        float cb = 0.f;
#pragma unroll
        for (int i = 0; i < 8; ++i) cb += c1[i] * W2[i * 32 + t];
        cw2[t] = cb;
    }
    if (t == 128) *(int4*)(ys1 + (size_t)N_NODES * 8) = make_int4(0, 0, 0, 0);
}

// ---------------- layer 2: 32 nodes/block, LDS-staged csr, fast/tail loop split ----------------

__global__ void k_agg2(const __half* __restrict__ ys1, const int* __restrict__ offs,
                       const int* __restrict__ ends, const int* __restrict__ csr,
                       const float* __restrict__ dis, const float* __restrict__ svec,
                       const float* __restrict__ W2p, const float* __restrict__ cw2,
                       const float* __restrict__ b2, __half* __restrict__ ys2,
                       float* __restrict__ part2) {
    __shared__ float sW[256], sC[32], sB[32], sm2[64];
    __shared__ int sidx[A2CAP], soff[32], send[32];
    int t = threadIdx.x;
    int n0 = blockIdx.x * 32;
    sW[t] = W2p[t];
    if (t < 32) {
        sC[t] = cw2[t]; sB[t] = b2[t];
        soff[t] = offs[n0 + t]; send[t] = ends[n0 + t];
    }
    if (t < 64) sm2[t] = 0.f;
    __syncthreads();
    int base = soff[0];
    int span = send[31] - base;
    int cap = min(span, A2CAP);
    for (int i = t; i < cap; i += 256) sidx[i] = csr[base + i];
    __syncthreads();

    int nl = t >> 3;          // node 0..31
    int lane8 = t & 7;        // 8 edge groups
    int node = n0 + nl;
    int rb = soff[nl] - base;
    int re = send[nl] - base;
    float a[8] = {0, 0, 0, 0, 0, 0, 0, 0};
    int r = rb + lane8;
    if (span <= A2CAP) {   // wave-uniform: no cap fallback predicate
        for (; r + 24 < re; r += 32) {   // fast path: all 4 slots valid, no guards
            int s0 = sidx[r], s1 = sidx[r + 8], s2i = sidx[r + 16], s3 = sidx[r + 24];
            h8s v0 = *(const h8s*)(ys1 + (size_t)s0 * 8);
            h8s v1 = *(const h8s*)(ys1 + (size_t)s1 * 8);
            h8s v2 = *(const h8s*)(ys1 + (size_t)s2i * 8);
            h8s v3 = *(const h8s*)(ys1 + (size_t)s3 * 8);
#pragma unroll
            for (int q = 0; q < 4; ++q) {
                a[2 * q] += __low2float(v0.h[q]) + __low2float(v1.h[q]) +
                            __low2float(v2.h[q]) + __low2float(v3.h[q]);
                a[2 * q + 1] += __high2float(v0.h[q]) + __high2float(v1.h[q]) +
                                __high2float(v2.h[q]) + __high2float(v3.h[q]);
            }
        }
        if (r < re) {   // single guarded tail
            int s[4];
#pragma unroll
            for (int j = 0; j < 4; ++j) {
                int rr = r + 8 * j;
                s[j] = (rr < re) ? sidx[rr] : N_NODES;
            }
            h8s v[4];
#pragma unroll
            for (int j = 0; j < 4; ++j) v[j] = *(const h8s*)(ys1 + (size_t)s[j] * 8);
#pragma unroll
            for (int j = 0; j < 4; ++j)
#pragma unroll
                for (int q = 0; q < 4; ++q) {
                    a[2 * q] += __low2float(v[j].h[q]);
                    a[2 * q + 1] += __high2float(v[j].h[q]);
                }
        }
    } else {   // generic path (practically never taken)
        for (; r < re; r += 32) {
            int s[4];
#pragma unroll
            for (int j = 0; j < 4; ++j) {
                int rr = r + 8 * j;
                s[j] = (rr < re) ? ((rr < A2CAP) ? sidx[rr] : csr[base + rr]) : N_NODES;
            }
            h8s v[4];
#pragma unroll
            for (int j = 0; j < 4; ++j) v[j] = *(const h8s*)(ys1 + (size_t)s[j] * 8);
#pragma unroll
            for (int j = 0; j < 4; ++j)
#pragma unroll
                for (int q = 0; q < 4; ++q) {
                    a[2 * q] += __low2float(v[j].h[q]);
                    a[2 * q + 1] += __high2float(v[j].h[q]);
                }
        }
    }
    if (lane8 == 0) {   // self-loop
        h8s v = *(const h8s*)(ys1 + (size_t)node * 8);
#pragma unroll
        for (int q = 0; q < 4; ++q) {
            a[2 * q] += __low2float(v.h[q]);
            a[2 * q + 1] += __high2float(v.h[q]);
        }
    }
#pragma unroll
    for (int off = 1; off < 8; off <<= 1)
#pragma unroll
        for (int k = 0; k < 8; ++k) a[k] += __shfl_xor(a[k], off, 64);
    int lane = t & 63;
    int nsub = lane >> 3;
    int lb = nsub << 3;
    float u[8];
#pragma unroll
    for (int i = 0; i < 8; ++i) u[i] = __shfl(a[i], lb, 64);
    float dn = dis[node];
    float sv = svec[node];
#pragma unroll
    for (int i = 0; i < 8; ++i) u[i] *= dn;
    int c0 = (lane & 7) * 4;
    float hh[4], hs2[4];
#pragma unroll
    for (int k = 0; k < 4; ++k) {
        int col = c0 + k;
        float conv = sB[col] + sv * sC[col];
#pragma unroll
        for (int i = 0; i < 8; ++i) conv += u[i] * sW[i * 32 + col];
        hh[k] = fmaxf(conv, 0.f);
        hs2[k] = hh[k] * hh[k];
    }
    h4 o;
    o.a = __floats2half2_rn(dn * hh[0], dn * hh[1]);
    o.b = __floats2half2_rn(dn * hh[2], dn * hh[3]);
    // plane-split store: plane = c0>>4, within-plane offset = c0&15
    *(h4*)(ys2 + (size_t)(c0 >> 4) * PLANE2 + (size_t)node * 16 + (c0 & 15)) = o;

    // fused BN stats (over pre-dn relu output): reduce across the 8 nodes of the wave
    float hs[4];
#pragma unroll
    for (int k = 0; k < 4; ++k) hs[k] = hh[k];
#pragma unroll
    for (int off = 8; off < 64; off <<= 1)
#pragma unroll
        for (int k = 0; k < 4; ++k) {
            hs[k] += __shfl_xor(hs[k], off, 64);
            hs2[k] += __shfl_xor(hs2[k], off, 64);
        }
    if (nsub == 0) {
#pragma unroll
        for (int k = 0; k < 4; ++k) {
            atomicAdd(&sm2[c0 + k], hs[k]);
            atomicAdd(&sm2[32 + c0 + k], hs2[k]);
        }
    }
    __syncthreads();
    if (t < 64) part2[(size_t)t * NB2P + blockIdx.x] = sm2[t];
}

__global__ void k_red32(const float* __restrict__ part2, float* __restrict__ stats2) {
    int i = blockIdx.x;   // 0..63
    int t = threadIdx.x;  // 256
    float s = 0.f;
    for (int b = t; b < NB2; b += 256) s += part2[(size_t)i * NB2P + b];
    __shared__ float sm[256];
    sm[t] = s;
    __syncthreads();
    for (int st = 128; st > 0; st >>= 1) {
        if (t < st) sm[t] += sm[t + st];
        __syncthreads();
    }
    if (t == 0) stats2[i] = sm[0];
}

// ---------------- prep3 ----------------

__global__ void k_prep3(const float* __restrict__ stats, const float* __restrict__ gamma,
                        const float* __restrict__ beta, const float* __restrict__ W3,
                        __half* __restrict__ wfrag, float* __restrict__ cw3,
                        __half* __restrict__ ys2) {
    __shared__ float a2[32], c2[32];
    int t = threadIdx.x;   // 512
    if (t < 32) {
        float inv_n = 1.0f / (float)N_NODES;
        float m = stats[t] * inv_n;
        float v = stats[32 + t] * inv_n - m * m;
        float a = gamma[t] * rsqrtf(v + BN_EPS);
        a2[t] = a;
        c2[t] = beta[t] - m * a;
    }
    __syncthreads();
    {
        int g = t >> 6, kq = (t >> 4) & 3, c = t & 15;
#pragma unroll
        for (int j = 0; j < 8; ++j) {
            int k = kq * 8 + j;
            wfrag[(size_t)t * 8 + j] = __float2half(a2[k] * W3[k * 128 + g * 16 + c]);
        }
    }
    if (t < 128) {
        float cb = 0.f;
#pragma unroll
        for (int k = 0; k < 32; ++k) cb += c2[k] * W3[k * 128 + t];
        cw3[t] = cb;
    }
    // zero sentinel row N in both ys2 planes (16 halves each)
    if (t >= 480 && t < 496) {
        int idx = t - 480;   // 0..15: plane = idx>>3, half2 slot = idx&7
        ((__half2*)(ys2 + (size_t)(idx >> 3) * PLANE2 + (size_t)N_NODES * 16))[idx & 7] =
            __half2{__float2half(0.f), __float2half(0.f)};
    }
}

// ---------------- layer 3 aggregation: 32 nodes / 512-thread block, LDS-staged csr ----------------
// plane = blockIdx&1 parity keeps one 3.2MB plane per XCD L2; fast/tail loop split.

__global__ void k_agg3(const __half* __restrict__ ys2, const int* __restrict__ offs,
                       const int* __restrict__ ends, const int* __restrict__ csr,
                       const float* __restrict__ dis, __half* __restrict__ u2) {
    __shared__ int sidx[A3CAP], soff[32], send[32];
    int plane = blockIdx.x & 1;
    int nb = blockIdx.x >> 1;
    int t = threadIdx.x;   // 512
    int n0 = nb * 32;
    if (t < 32) { soff[t] = offs[n0 + t]; send[t] = ends[n0 + t]; }
    __syncthreads();
    int base = soff[0];
    int span = send[31] - base;
    int cap = min(span, A3CAP);
    for (int i = t; i < cap; i += 512) sidx[i] = csr[base + i];
    __syncthreads();

    int nl = t >> 4;          // node 0..31
    int lane16 = t & 15;
    int eg = lane16 >> 1;     // 8 edge groups
    int chunk = lane16 & 1;   // 2 x 16B per 32B row
    int node = n0 + nl;
    int rb = soff[nl] - base;
    int re = send[nl] - base;
    float a[8] = {0, 0, 0, 0, 0, 0, 0, 0};
    const __half* hp = ys2 + (size_t)plane * PLANE2 + chunk * 8;
    int r = rb + eg;
    if (span <= A3CAP) {   // wave-uniform specialization: no cap fallback
        for (; r + 24 < re; r += 32) {   // fast path: no guards
            int s0 = sidx[r], s1 = sidx[r + 8], s2i = sidx[r + 16], s3 = sidx[r + 24];
            h8s v0 = *(const h8s*)(hp + (size_t)s0 * 16);
            h8s v1 = *(const h8s*)(hp + (size_t)s1 * 16);
            h8s v2 = *(const h8s*)(hp + (size_t)s2i * 16);
            h8s v3 = *(const h8s*)(hp + (size_t)s3 * 16);
#pragma unroll
            for (int q = 0; q < 4; ++q) {
                a[2 * q] += __low2float(v0.h[q]) + __low2float(v1.h[q]) +
                            __low2float(v2.h[q]) + __low2float(v3.h[q]);
                a[2 * q + 1] += __high2float(v0.h[q]) + __high2float(v1.h[q]) +
                                __high2float(v2.h[q]) + __high2float(v3.h[q]);
            }
        }
        if (r < re) {   // single guarded tail
            int s[4];
#pragma unroll
            for (int j = 0; j < 4; ++j) {
                int rr = r + 8 * j;
                s[j] = (rr < re) ? sidx[rr] : N_NODES;
            }
            h8s v[4];
#pragma unroll
            for (int j = 0; j < 4; ++j) v[j] = *(const h8s*)(hp + (size_t)s[j] * 16);
#pragma unroll
            for (int j = 0; j < 4; ++j)
#pragma unroll
                for (int q = 0; q < 4; ++q) {
                    a[2 * q] += __low2float(v[j].h[q]);
                    a[2 * q + 1] += __high2float(v[j].h[q]);
                }
        }
    } else {   // generic path (practically never taken)
        for (; r < re; r += 32) {
            int s[4];
#pragma unroll
            for (int j = 0; j < 4; ++j) {
                int rr = r + 8 * j;
                s[j] = (rr < re) ? ((rr < A3CAP) ? sidx[rr] : csr[base + rr]) : N_NODES;
            }
            h8s v[4];
#pragma unroll
            for (int j = 0; j < 4; ++j) v[j] = *(const h8s*)(hp + (size_t)s[j] * 16);
#pragma unroll
            for (int j = 0; j < 4; ++j)
#pragma unroll
                for (int q = 0; q < 4; ++q) {
                    a[2 * q] += __low2float(v[j].h[q]);
                    a[2 * q + 1] += __high2float(v[j].h[q]);
                }
        }
    }
    if (eg == 0) {   // self-loop: both chunk lanes load their 16B half
        h8s v = *(const h8s*)(hp + (size_t)node * 16);
#pragma unroll
        for (int q = 0; q < 4; ++q) {
            a[2 * q] += __low2float(v.h[q]);
            a[2 * q + 1] += __high2float(v.h[q]);
        }
    }
    // reduce over eg (tid bits 1-3)
#pragma unroll
    for (int off = 2; off < 16; off <<= 1)
#pragma unroll
        for (int k = 0; k < 8; ++k) a[k] += __shfl_xor(a[k], off, 64);
    if (eg == 0) {
        float dn = dis[node];
        h8s o;
#pragma unroll
        for (int q = 0; q < 4; ++q)
            o.h[q] = __floats2half2_rn(dn * a[2 * q], dn * a[2 * q + 1]);
        *(h8s*)(u2 + (size_t)plane * PLANEU + (size_t)node * 16 + chunk * 8) = o;
    }
}

// ---------------- layer 3 transform via MFMA + fused BN-stats + fused POOLING ----------------

__global__ void k_mm_mfma(const __half* __restrict__ u2, const __half* __restrict__ wfrag,
                          const float* __restrict__ cw3, const float* __restrict__ b3,
                          const float* __restrict__ svec, const int* __restrict__ batch,
                          float* __restrict__ spart, int* __restrict__ gmax,
                          int* __restrict__ gmin) {
    __shared__ float sm[256];
    int t = threadIdx.x;
    int wave = t >> 6;
    int lane = t & 63;
    int n0 = (blockIdx.x * 4 + wave) * 16;
    bool active = n0 < N_NODES;
    int m = lane & 15;
    int kq = lane >> 4;
    float ss[8] = {0, 0, 0, 0, 0, 0, 0, 0};
    float ss2[8] = {0, 0, 0, 0, 0, 0, 0, 0};

    if (active) {
        half8_t af = *(const half8_t*)(u2 + (size_t)(kq >> 1) * PLANEU +
                                       (size_t)(n0 + m) * 16 + (kq & 1) * 8);
        float4_t accs[8];
#pragma unroll
        for (int g = 0; g < 8; ++g) {
            float4_t acc = {0.f, 0.f, 0.f, 0.f};
            half8_t bf = *(const half8_t*)(wfrag + (size_t)((g * 4 + kq) * 16 + m) * 8);
            accs[g] = __builtin_amdgcn_mfma_f32_16x16x32_f16(af, bf, acc, 0, 0, 0);
        }
        float sv[4];
#pragma unroll
        for (int r = 0; r < 4; ++r) sv[r] = svec[n0 + kq * 4 + r];

        int b_first = batch[n0];
        int b_last = batch[n0 + 15];
        bool uni = (b_first == b_last);
        int bnr[4];
        if (!uni) {
#pragma unroll
            for (int r = 0; r < 4; ++r) bnr[r] = batch[n0 + kq * 4 + r];
        }
        float ymx[8], ymn[8];
#pragma unroll
        for (int g = 0; g < 8; ++g) {
            float cwf = cw3[g * 16 + m];
            float bf3 = b3[g * 16 + m];
            float mx = 0.f, mn = INFINITY;
#pragma unroll
            for (int r = 0; r < 4; ++r) {
                float y = fmaxf(accs[g][r] + sv[r] * cwf + bf3, 0.f);
                ss[g] += y;
                ss2[g] += y * y;
                mx = fmaxf(mx, y);
                mn = fminf(mn, y);
                if (!uni) {
                    int yb = __float_as_int(y);
                    atomicMax(&gmax[bnr[r] * 128 + g * 16 + m], yb);
                    atomicMin(&gmin[bnr[r] * 128 + g * 16 + m], yb);
                }
            }
            ymx[g] = mx;
            ymn[g] = mn;
        }
        if (uni) {
#pragma unroll
            for (int off = 16; off < 64; off <<= 1)
#pragma unroll
                for (int g = 0; g < 8; ++g) {
                    ymx[g] = fmaxf(ymx[g], __shfl_xor(ymx[g], off, 64));
                    ymn[g] = fminf(ymn[g], __shfl_xor(ymn[g], off, 64));
                }
            if (kq == 0) {
#pragma unroll
                for (int g = 0; g < 8; ++g) {
                    atomicMax(&gmax[b_first * 128 + g * 16 + m], __float_as_int(ymx[g]));
                    atomicMin(&gmin[b_first * 128 + g * 16 + m], __float_as_int(ymn[g]));
                }
            }
        }
    }
#pragma unroll
    for (int off = 16; off < 64; off <<= 1)
#pragma unroll
        for (int g = 0; g < 8; ++g) {
            ss[g] += __shfl_xor(ss[g], off, 64);
            ss2[g] += __shfl_xor(ss2[g], off, 64);
        }
    sm[t] = 0.f;
    __syncthreads();
    if (active && kq == 0) {
#pragma unroll
        for (int g = 0; g < 8; ++g) {
            atomicAdd(&sm[g * 16 + m], ss[g]);
            atomicAdd(&sm[128 + g * 16 + m], ss2[g]);
        }
    }
    __syncthreads();
    spart[(size_t)blockIdx.x * 256 + t] = sm[t];
}

__global__ void k_stats_red(const float* __restrict__ part, float* __restrict__ stats) {
    int i = blockIdx.x;   // 0..255
    int t = threadIdx.x;  // 256
    float s = 0.f;
    for (int b = t; b < NMMB; b += 256) s += part[(size_t)b * 256 + i];
    __shared__ float sm[256];
    sm[t] = s;
    __syncthreads();
    for (int st = 128; st > 0; st >>= 1) {
        if (t < st) sm[t] += sm[t + st];
        __syncthreads();
    }
    if (t == 0) stats[i] = sm[0];
}

// ---------------- fused bn-affine + head + log_softmax ----------------

__device__ __forceinline__ int lower_bound_dev(const int* __restrict__ a, int val) {
    int lo = 0, hi = N_NODES;
    while (lo < hi) {
        int mid = (lo + hi) >> 1;
        if (a[mid] < val) lo = mid + 1; else hi = mid;
    }
    return lo;
}

__global__ void k_poolhead(const int* __restrict__ gmax, const int* __restrict__ gmin,
                           const int* __restrict__ batch, const float* __restrict__ stats,
                           const float* __restrict__ gamma, const float* __restrict__ beta,
                           const float* __restrict__ Wl, const float* __restrict__ bl,
                           float* __restrict__ out) {
    int g = blockIdx.x;
    int f = threadIdx.x;    // 128
    float inv_n = 1.0f / (float)N_NODES;
    float m = stats[f] * inv_n;
    float var = stats[128 + f] * inv_n - m * m;
    float a = gamma[f] * rsqrtf(var + BN_EPS);
    float c = beta[f] - m * a;
    int s = lower_bound_dev(batch, g);
    int e = lower_bound_dev(batch, g + 1);
    float mx = __int_as_float(gmax[g * 128 + f]);
    float mn = __int_as_float(gmin[g * 128 + f]);
    float r;
    if (e > s) r = (a >= 0.f) ? (a * mx + c) : (a * mn + c);
    else r = -INFINITY;
    __shared__ float l[3][128];
    l[0][f] = r * Wl[f * 3 + 0];
    l[1][f] = r * Wl[f * 3 + 1];
    l[2][f] = r * Wl[f * 3 + 2];
    __syncthreads();
    for (int st = 64; st > 0; st >>= 1) {
        if (f < st) {
            l[0][f] += l[0][f + st];
            l[1][f] += l[1][f + st];
            l[2][f] += l[2][f + st];
        }
        __syncthreads();
    }
    if (f == 0) {
        float l0 = l[0][0] + bl[0], l1 = l[1][0] + bl[1], l2 = l[2][0] + bl[2];
        float mxl = fmaxf(l0, fmaxf(l1, l2));
        float lse = mxl + logf(expf(l0 - mxl) + expf(l1 - mxl) + expf(l2 - mxl));
        out[g * 3 + 0] = l0 - lse;
        out[g * 3 + 1] = l1 - lse;
        out[g * 3 + 2] = l2 - lse;
    }
}

// ---------------- launch ----------------

extern "C" void kernel_launch(void* const* d_in, const int* in_sizes, int n_in,
                              void* d_out, int out_size, void* d_ws, size_t ws_size,
                              hipStream_t stream) {
    const float* x   = (const float*)d_in[0];
    const int* ei    = (const int*)d_in[1];
    const int* src   = ei;
    const int* dst   = ei + N_EDGES;
    const int* batch = (const int*)d_in[2];
    const float *W1 = (const float*)d_in[3],  *b1 = (const float*)d_in[4];
    const float *g1 = (const float*)d_in[5],  *be1 = (const float*)d_in[6];
    const float *W2 = (const float*)d_in[7],  *b2 = (const float*)d_in[8];
    const float *g2 = (const float*)d_in[9],  *be2 = (const float*)d_in[10];
    const float *W3 = (const float*)d_in[11], *b3 = (const float*)d_in[12];
    const float *g3 = (const float*)d_in[13], *be3 = (const float*)d_in[14];
    const float *Wl = (const float*)d_in[15], *bl = (const float*)d_in[16];
    float* out = (float*)d_out;

    // workspace carve (4-byte words)
    int* base = (int*)d_ws;
    size_t o = 0;
    float* stats1 = (float*)(base + o); o += 256;
    float* stats2 = (float*)(base + o); o += 256;
    float* stats3 = (float*)(base + o); o += 256;
    int* gmax     = base + o; o += (size_t)N_GRAPHS * 128;
    size_t zero_words = o;                         // zeroed region
    int* gmin     = base + o; o += (size_t)N_GRAPHS * 128;   // memset 0x7F
    int* bbase    = base + o; o += NBIN + 4;
    int* ghist    = base + o; o += NBIN + 4;
    int* hists    = base + o; o += ((size_t)NBIN * NCHUNK + 3) & ~3ULL;
    float* W2p    = (float*)(base + o); o += 256;
    float* cw2    = (float*)(base + o); o += 32;
    __half* wfrag = (__half*)(base + o); o += 2048;
    float* cw3    = (float*)(base + o); o += 128;
    int* offs     = base + o; o += 100000;
    int* ends     = base + o; o += 100000;
    int* store    = base + o; o += STORE_CAP;
    int* csr      = base + o; o += STORE_CAP;
    float* dis    = (float*)(base + o); o += N_NODES;
    float* rdis   = (float*)(base + o); o += N_NODES;
    float* svec   = (float*)(base + o); o += N_NODES;
    float* spart  = (float*)(base + o); o += (size_t)NMMB * 256;
    float* part2  = (float*)(base + o); o += (size_t)64 * NB2P;
    float4* xd    = (float4*)(base + o); o += (size_t)(N_NODES + 1) * 4;
    __half* ys1   = (__half*)(base + o); o += (size_t)(N_NODES + 1) * 4;
    __half* ys2   = (__half*)(base + o); o += (size_t)(N_NODES + 1) * 16;  // 2 planes
    __half* u2    = (__half*)(base + o); o += (size_t)N_NODES * 16;        // 2 planes
    if (ws_size < o * 4) return;

    const int TB = 256;

    hipMemsetAsync(base, 0, zero_words * 4, stream);
    hipMemsetAsync(gmin, 0x7F, (size_t)N_GRAPHS * 128 * 4, stream);

    // CSR build (padded radix, 512-node bins, direct scatter)
    k_hist2<<<NCHUNK, 1024, 0, stream>>>(dst, hists);
    k_scan2<<<NBIN, 64, 0, stream>>>(hists, ghist);
    k_binscan<<<1, 512, 0, stream>>>(ghist, bbase);
    k_scatter<<<NCHUNK, 1024, 0, stream>>>(src, dst, bbase, hists, store);
    k_csr_build<<<NBIN, 1024, 0, stream>>>(bbase, store, x, offs, ends, dis, rdis, xd, csr);

    // layer 1 (32 nodes/block, LDS-staged csr, fast/tail split)
    k_agg1<<<N_NODES / 32, TB, 0, stream>>>(xd, offs, ends, csr, W1, b1, svec, ys1);
    k_stats8v<<<64, 256, 0, stream>>>(ys1, rdis, stats1);
    k_prep2<<<1, 256, 0, stream>>>(stats1, g1, be1, W2, W2p, cw2, ys1);

    // layer 2 (32 nodes/block, LDS-staged csr, fast/tail split) with fused BN-stats
    k_agg2<<<NB2, TB, 0, stream>>>(ys1, offs, ends, csr, dis, svec, W2p, cw2, b2, ys2, part2);
    k_red32<<<64, 256, 0, stream>>>(part2, stats2);
    k_prep3<<<1, 512, 0, stream>>>(stats2, g2, be2, W3, wfrag, cw3, ys2);

    // layer 3: 32 nodes / 512-thread block; plane = blockIdx&1 keeps one plane per XCD L2
    k_agg3<<<2 * (N_NODES / 32), 512, 0, stream>>>(ys2, offs, ends, csr, dis, u2);
    k_mm_mfma<<<NMMB, 256, 0, stream>>>(u2, wfrag, cw3, b3, svec, batch, spart, gmax, gmin);
    k_stats_red<<<256, 256, 0, stream>>>(spart, stats3);

    // head
    k_poolhead<<<N_GRAPHS, 128, 0, stream>>>(gmax, gmin, batch, stats3, g3, be3, Wl, bl, out);
}